// Round 5
// baseline (256.220 us; speedup 1.0000x reference)
//
#include <hip/hip_runtime.h>
#include <hip/hip_bf16.h>
#include <stdint.h>

// Problem constants (fixed by setup_inputs): B=D=O=4096, m=2048
#define D_DIM     4096
#define MB        2048   // M_BUCKETS = K of the GEMM
#define NROWS     4096   // B == O == 4096
#define K_DIM     MB

typedef __bf16 bf16x8 __attribute__((ext_vector_type(8)));
typedef float  floatx4 __attribute__((ext_vector_type(4)));

// async global->LDS, 16B per lane. ONLY used in wave-uniform-base + lane*16
// destination form (R4 post-mortem: non-linear dest -> device fault).
__device__ __forceinline__ void gld_lds16(const void* g, void* l) {
    __builtin_amdgcn_global_load_lds(
        (const __attribute__((address_space(1))) unsigned int*)g,
        (__attribute__((address_space(3))) unsigned int*)l,
        16, 0, 0);
}

// ---------------------------------------------------------------------------
// Kernel 1: invert hash_idx into bucket-sorted permutation + descriptors.
// (unchanged, proven)
// ---------------------------------------------------------------------------
__global__ __launch_bounds__(256) void build_csr(
    const int* __restrict__ hash_idx,
    unsigned int* __restrict__ desc,       // [MB]
    unsigned short* __restrict__ perm16)   // [D_DIM]
{
    __shared__ int cnt[MB];
    __shared__ int scan[MB];
    const int t = threadIdx.x;

    for (int k = t; k < MB; k += 256) cnt[k] = 0;
    __syncthreads();
    for (int j = t; j < D_DIM; j += 256) atomicAdd(&cnt[hash_idx[j]], 1);
    __syncthreads();
    for (int k = t; k < MB; k += 256) scan[k] = cnt[k];
    __syncthreads();
    for (int stride = 1; stride < MB; stride <<= 1) {
        int vals[8];
        #pragma unroll
        for (int i = 0; i < 8; ++i) {
            int k = t + 256 * i;
            vals[i] = (k >= stride) ? scan[k - stride] : 0;
        }
        __syncthreads();
        #pragma unroll
        for (int i = 0; i < 8; ++i) scan[t + 256 * i] += vals[i];
        __syncthreads();
    }
    for (int k = t; k < MB; k += 256) {
        int excl = scan[k] - cnt[k];
        desc[k] = ((unsigned)excl << 16) | (unsigned)cnt[k];
        cnt[k] = excl;                      // becomes scatter cursor
    }
    __syncthreads();
    for (int j = t; j < D_DIM; j += 256) {
        int k = hash_idx[j];
        int pos = atomicAdd(&cnt[k], 1);
        perm16[pos] = (unsigned short)j;    // in-bucket order irrelevant
    }
}

// ---------------------------------------------------------------------------
// Kernel 2: countsketch (unchanged, proven)
// ---------------------------------------------------------------------------
__global__ __launch_bounds__(256) void sketch_gather(
    const float* __restrict__ input,    // [4096][4096]
    const float* __restrict__ weight,   // [4096][4096]
    const float* __restrict__ rand_sgn, // [4096]
    const unsigned int* __restrict__ desc,
    const unsigned short* __restrict__ perm16,
    __hip_bfloat16* __restrict__ sk_in, // [4096][2048]
    __hip_bfloat16* __restrict__ sk_w)  // [4096][2048]
{
    __shared__ __align__(16) float rv0[D_DIM + 8];          // 16.03 KB
    __shared__ __align__(16) float rv1[D_DIM + 8];          // 16.03 KB
    __shared__ __align__(16) unsigned short perm[D_DIM];    // 8 KB
    const int b = blockIdx.x;
    const bool is_w = (b >= NROWS / 2);
    const int pr = is_w ? (b - NROWS / 2) : b;              // row-pair index
    const float* src = (is_w ? weight : input) + (size_t)pr * 2 * D_DIM;
    __hip_bfloat16* dst = (is_w ? sk_w : sk_in) + (size_t)pr * 2 * MB;
    const int t = threadIdx.x;

    const uint4* pg = (const uint4*)perm16;
    ((uint4*)perm)[t]       = pg[t];
    ((uint4*)perm)[t + 256] = pg[t + 256];

    const float4* s4 = (const float4*)src;
    const float4* g4 = (const float4*)rand_sgn;
    #pragma unroll
    for (int i = 0; i < 4; ++i) {
        int q = t + 256 * i;                // float4 granule 0..1023
        float4 g = g4[q];
        float4 x0 = s4[q], x1 = s4[q + 1024];
        float4 y0; y0.x = x0.x*g.x; y0.y = x0.y*g.y; y0.z = x0.z*g.z; y0.w = x0.w*g.w;
        float4 y1; y1.x = x1.x*g.x; y1.y = x1.y*g.y; y1.z = x1.z*g.z; y1.w = x1.w*g.w;
        *(float4*)&rv0[4 * q] = y0;
        *(float4*)&rv1[4 * q] = y1;
    }
    __syncthreads();

    float4 a0[4], a1[4];
    #pragma unroll
    for (int i = 0; i < 4; ++i) {
        int q = t + 256 * i;                // quad of perm slots
        ushort4 pp = *(const ushort4*)&perm[4 * q];
        a0[i].x = rv0[pp.x]; a0[i].y = rv0[pp.y];
        a0[i].z = rv0[pp.z]; a0[i].w = rv0[pp.w];
        a1[i].x = rv1[pp.x]; a1[i].y = rv1[pp.y];
        a1[i].z = rv1[pp.z]; a1[i].w = rv1[pp.w];
    }
    __syncthreads();
    #pragma unroll
    for (int i = 0; i < 4; ++i) {
        int q = t + 256 * i;
        *(float4*)&rv0[4 * q] = a0[i];
        *(float4*)&rv1[4 * q] = a1[i];
    }
    __syncthreads();

    #pragma unroll
    for (int i = 0; i < 8; ++i) {
        int k = t + 256 * i;
        unsigned d = desc[k];
        int st = (int)(d >> 16), c = (int)(d & 0xFFFF);
        float s0 = 0.f, s1 = 0.f;
        #pragma unroll
        for (int j = 0; j < 8; ++j) {
            float v0 = rv0[st + j], v1 = rv1[st + j];
            bool m = (j < c);
            s0 += m ? v0 : 0.f;
            s1 += m ? v1 : 0.f;
        }
        for (int j = 8; j < c; ++j) {
            s0 += rv0[st + j]; s1 += rv1[st + j];
        }
        dst[k]      = __float2bfloat16(s0);
        dst[MB + k] = __float2bfloat16(s1);
    }
}

// ---------------------------------------------------------------------------
// Kernel 3: C = A * B^T + bias. 256x256 tile, BK=64, 8 waves (2Mx4N),
// 8-phase schedule (T3), counted vmcnt(4) (T4), 3-bit row-XOR swizzle (T2,
// 0 conflicts verified R4), setprio (T5). 128 KiB LDS, dbuf K-tiles.
//
// R4 post-mortem: conflicts 7.34M->0 but dur only -2% -> staging from
// LLC (L2 thrash: linear dispatch gives each XCD 16 B-panels + 2 A-panels
// = 18MB >> 4MB L2) was the real stall. Fixes this round:
//  (a) XCD rectangle remap (T1): linear wg id lid -> xcd=lid&7 owns an
//      8bx x 4by rectangle -> concurrent K-slice set 384KB << 4MB L2.
//  (b) hold BOTH B quadrants in regs (bfr0/bfr1, +16 VGPR): ph4/ph8 lose
//      their re-LOAD_B -> 24KB LDS reads/wave/K-tile, pure-MFMA ph4/ph8.
// Read timings strict subset of R4's; staging untouched -> R2 hazard audit
// (ph4-wait covers all but ph3/ph4 stages; ph8-wait all but ph7/ph8) holds.
// ---------------------------------------------------------------------------
#define LDSA(p, h) (lds + (p)*32768 + (h)*16384)
#define LDSB(p, h) (lds + 65536 + (p)*32768 + (h)*16384)
#define SWZ(L) ((L) ^ ((((L) >> 7) & 7) << 4))

#define BAR() do { __builtin_amdgcn_sched_barrier(0); \
                   __builtin_amdgcn_s_barrier(); \
                   __builtin_amdgcn_sched_barrier(0); } while (0)
#define VMCNT4() asm volatile("s_waitcnt vmcnt(4)" ::: "memory")

// stage A region mh of K-tile kt into buffer p (2 x gld_lds16)
#define STAGE_A(p, mh, kt) do { \
    int L_ = (mh)*8192 + t*16; \
    int P_ = SWZ(L_); \
    const char* s_ = Ab + (size_t)(rowBase + (P_ >> 7)) * 4096 \
                        + (size_t)((((kt) & 31) * 128) + (P_ & 127)); \
    gld_lds16(s_,                       LDSA(p, 0) + L_); \
    gld_lds16(s_ + (size_t)128 * 4096,  LDSA(p, 1) + L_); \
} while (0)

// stage B region nh of K-tile kt into buffer p
#define STAGE_B(p, nh, kt) do { \
    int L_ = (t >> 8) * 8192 + (nh)*4096 + (t & 255) * 16; \
    int P_ = SWZ(L_); \
    const char* s_ = Bb + (size_t)(colBase + (P_ >> 7)) * 4096 \
                        + (size_t)((((kt) & 31) * 128) + (P_ & 127)); \
    gld_lds16(s_,                       LDSB(p, 0) + L_); \
    gld_lds16(s_ + (size_t)128 * 4096,  LDSB(p, 1) + L_); \
} while (0)

// load A fragments for quadrant mh from buffer p (8 x ds_read_b128)
#define LOAD_A(p, mh) do { \
    const char* ba_ = LDSA(p, wm); \
    _Pragma("unroll") \
    for (int i_ = 0; i_ < 4; ++i_) { \
        int r_ = (mh)*64 + i_*16 + mrow; \
        _Pragma("unroll") \
        for (int kk_ = 0; kk_ < 2; ++kk_) { \
            int L_ = r_*128 + kk_*64 + quad*16; \
            af[i_][kk_] = *(const bf16x8*)(ba_ + SWZ(L_)); \
        } \
    } \
} while (0)

// load B fragments for quadrant nh from buffer p into reg set BF
#define LOAD_B(p, nh, BF) do { \
    const char* bb_ = LDSB(p, wn >> 1); \
    _Pragma("unroll") \
    for (int j_ = 0; j_ < 2; ++j_) { \
        int r_ = (wn & 1)*64 + (nh)*32 + j_*16 + mrow; \
        _Pragma("unroll") \
        for (int kk_ = 0; kk_ < 2; ++kk_) { \
            int L_ = r_*128 + kk_*64 + quad*16; \
            BF[j_][kk_] = *(const bf16x8*)(bb_ + SWZ(L_)); \
        } \
    } \
} while (0)

// 16 MFMA: quadrant (mh,nh) x K=64 from reg set BF, setprio-wrapped (T5)
#define MFMA_Q(mh, nh, BF) do { \
    __builtin_amdgcn_s_setprio(1); \
    _Pragma("unroll") \
    for (int i_ = 0; i_ < 4; ++i_) \
        _Pragma("unroll") \
        for (int j_ = 0; j_ < 2; ++j_) \
            _Pragma("unroll") \
            for (int kk_ = 0; kk_ < 2; ++kk_) \
                acc[(mh)*4 + i_][(nh)*2 + j_] = \
                    __builtin_amdgcn_mfma_f32_16x16x32_bf16( \
                        af[i_][kk_], BF[j_][kk_], \
                        acc[(mh)*4 + i_][(nh)*2 + j_], 0, 0, 0); \
    __builtin_amdgcn_s_setprio(0); \
} while (0)

__global__ __launch_bounds__(512, 2) void gemm_bt_bias(
    const __hip_bfloat16* __restrict__ A,   // [4096][2048]
    const __hip_bfloat16* __restrict__ B,   // [4096][2048]
    const float* __restrict__ bias,         // [4096]
    float* __restrict__ C)                  // [4096][4096]
{
    __shared__ __align__(16) char lds[131072];   // A: 2x2x16KB | B: 2x2x16KB
    const char* Ab = (const char*)A;
    const char* Bb = (const char*)B;

    const int t = threadIdx.x;
    const int lane = t & 63;
    const int wid  = t >> 6;        // 0..7
    const int wm = wid >> 2;        // 0..1
    const int wn = wid & 3;         // 0..3
    const int quad = lane >> 4;
    const int mrow = lane & 15;

    // XCD rectangle remap (T1): lid%8 = XCD under round-robin dispatch.
    // Each XCD gets an 8(bx) x 4(by) rectangle: L2 K-slice set = 384 KB.
    const int lid  = blockIdx.y * 16 + blockIdx.x;
    const int xcd  = lid & 7;
    const int slot = lid >> 3;                       // 0..31
    const int bx   = (xcd & 1) * 8 + (slot & 7);     // 0..15
    const int by   = (xcd >> 1) * 4 + (slot >> 3);   // 0..15
    const int rowBase = by * 256;
    const int colBase = bx * 256;

    bf16x8 af[4][2];                // A frags, current mh quadrant
    bf16x8 bfr0[2][2];              // B frags, nh=0 (held ph1..ph4)
    bf16x8 bfr1[2][2];              // B frags, nh=1
    floatx4 acc[8][4];
    const floatx4 zero = {0.f, 0.f, 0.f, 0.f};
    #pragma unroll
    for (int i = 0; i < 8; ++i)
        #pragma unroll
        for (int j = 0; j < 4; ++j) acc[i][j] = zero;

    // prologue: kt0 fully (A0,B1,B0,A1 -> buf0), kt1 partially (A0,B1 -> buf1)
    STAGE_A(0, 0, 0); STAGE_B(0, 1, 0); STAGE_B(0, 0, 0); STAGE_A(0, 1, 0);
    STAGE_A(1, 0, 1); STAGE_B(1, 1, 1);
    VMCNT4();          // kt0's 8 loads confirmed; kt1's 4 may fly
    BAR();

    #pragma unroll 1
    for (int it = 0; it < 16; ++it) {
        const int kt = 2 * it;
        // ph1: compute kt.Q(0,0) from buf0; stage kt+1.B0 -> buf1
        LOAD_A(0, 0); LOAD_B(0, 0, bfr0); STAGE_B(1, 0, kt + 1);
        BAR(); MFMA_Q(0, 0, bfr0); BAR();
        // ph2: Q(0,1); stage kt+1.A1 -> buf1
        LOAD_B(0, 1, bfr1); STAGE_A(1, 1, kt + 1);
        BAR(); MFMA_Q(0, 1, bfr1); BAR();
        // ph3: Q(1,1), reuse bfr1; stage kt+2.A0 -> buf0 (A0 free after ph2)
        LOAD_A(0, 1); STAGE_A(0, 0, kt + 2);
        BAR(); MFMA_Q(1, 1, bfr1); BAR();
        // ph4: Q(1,0), reuse bfr0 (no LDS reads); stage kt+2.B1 -> buf0
        STAGE_B(0, 1, kt + 2);
        BAR(); MFMA_Q(1, 0, bfr0); VMCNT4(); BAR();
        // ph5: compute kt+1.Q(0,0) from buf1; stage kt+2.B0 -> buf0
        LOAD_A(1, 0); LOAD_B(1, 0, bfr0); STAGE_B(0, 0, kt + 2);
        BAR(); MFMA_Q(0, 0, bfr0); BAR();
        // ph6: Q(0,1); stage kt+2.A1 -> buf0
        LOAD_B(1, 1, bfr1); STAGE_A(0, 1, kt + 2);
        BAR(); MFMA_Q(0, 1, bfr1); BAR();
        // ph7: Q(1,1), reuse bfr1; stage kt+3.A0 -> buf1 (A0 free after ph6)
        LOAD_A(1, 1); STAGE_A(1, 0, kt + 3);
        BAR(); MFMA_Q(1, 1, bfr1); BAR();
        // ph8: Q(1,0), reuse bfr0 (no LDS reads); stage kt+3.B1 -> buf1
        STAGE_B(1, 1, kt + 3);
        BAR(); MFMA_Q(1, 0, bfr0); VMCNT4(); BAR();
    }

    // epilogue: C/D layout col=lane&15, row=quad*4+reg  [m89/m91]
    float bj[4];
    #pragma unroll
    for (int j = 0; j < 4; ++j)
        bj[j] = bias[colBase + wn * 64 + j * 16 + mrow];
    #pragma unroll
    for (int i = 0; i < 8; ++i) {
        int m0 = rowBase + wm * 128 + i * 16 + quad * 4;
        #pragma unroll
        for (int j = 0; j < 4; ++j) {
            int n = colBase + wn * 64 + j * 16 + mrow;
            #pragma unroll
            for (int p = 0; p < 4; ++p)
                C[(size_t)(m0 + p) * NROWS + n] = acc[i][j][p] + bj[j];
        }
    }
}

// ---------------------------------------------------------------------------
extern "C" void kernel_launch(void* const* d_in, const int* in_sizes, int n_in,
                              void* d_out, int out_size, void* d_ws, size_t ws_size,
                              hipStream_t stream) {
    const float* input  = (const float*)d_in[0];
    const float* weight = (const float*)d_in[1];
    const float* bias   = (const float*)d_in[2];
    const int*   hidx   = (const int*)d_in[3];
    const float* sgn    = (const float*)d_in[4];
    float* out = (float*)d_out;

    // workspace: sk_in 16MB | sk_w 16MB | desc 8KB | perm16 8KB
    char* ws = (char*)d_ws;
    __hip_bfloat16* sk_in = (__hip_bfloat16*)ws;
    __hip_bfloat16* sk_w  = (__hip_bfloat16*)(ws + (size_t)16 * 1024 * 1024);
    unsigned int*   desc  = (unsigned int*)(ws + (size_t)32 * 1024 * 1024);
    unsigned short* perm16 = (unsigned short*)(ws + (size_t)32 * 1024 * 1024 + 8192);

    build_csr<<<1, 256, 0, stream>>>(hidx, desc, perm16);
    sketch_gather<<<NROWS, 256, 0, stream>>>(input, weight, sgn, desc, perm16,
                                             sk_in, sk_w);
    gemm_bt_bias<<<dim3(16, 16), 512, 0, stream>>>(sk_in, sk_w, bias, out);
}

// Round 6
// 249.398 us; speedup vs baseline: 1.0274x; 1.0274x over previous
//
#include <hip/hip_runtime.h>
#include <hip/hip_bf16.h>
#include <stdint.h>

// Problem constants (fixed by setup_inputs): B=D=O=4096, m=2048
#define D_DIM     4096
#define MB        2048   // M_BUCKETS = K of the GEMM
#define NROWS     4096   // B == O == 4096
#define K_DIM     MB

typedef __bf16 bf16x8 __attribute__((ext_vector_type(8)));
typedef float  floatx4 __attribute__((ext_vector_type(4)));

// async global->LDS, 16B per lane. ONLY used in wave-uniform-base + lane*16
// destination form (R4 post-mortem: non-linear dest -> device fault).
__device__ __forceinline__ void gld_lds16(const void* g, void* l) {
    __builtin_amdgcn_global_load_lds(
        (const __attribute__((address_space(1))) unsigned int*)g,
        (__attribute__((address_space(3))) unsigned int*)l,
        16, 0, 0);
}

// ---------------------------------------------------------------------------
// Kernel 1: invert hash_idx into bucket-sorted permutation + descriptors.
// (unchanged, proven)
// ---------------------------------------------------------------------------
__global__ __launch_bounds__(256) void build_csr(
    const int* __restrict__ hash_idx,
    unsigned int* __restrict__ desc,       // [MB]
    unsigned short* __restrict__ perm16)   // [D_DIM]
{
    __shared__ int cnt[MB];
    __shared__ int scan[MB];
    const int t = threadIdx.x;

    for (int k = t; k < MB; k += 256) cnt[k] = 0;
    __syncthreads();
    for (int j = t; j < D_DIM; j += 256) atomicAdd(&cnt[hash_idx[j]], 1);
    __syncthreads();
    for (int k = t; k < MB; k += 256) scan[k] = cnt[k];
    __syncthreads();
    for (int stride = 1; stride < MB; stride <<= 1) {
        int vals[8];
        #pragma unroll
        for (int i = 0; i < 8; ++i) {
            int k = t + 256 * i;
            vals[i] = (k >= stride) ? scan[k - stride] : 0;
        }
        __syncthreads();
        #pragma unroll
        for (int i = 0; i < 8; ++i) scan[t + 256 * i] += vals[i];
        __syncthreads();
    }
    for (int k = t; k < MB; k += 256) {
        int excl = scan[k] - cnt[k];
        desc[k] = ((unsigned)excl << 16) | (unsigned)cnt[k];
        cnt[k] = excl;                      // becomes scatter cursor
    }
    __syncthreads();
    for (int j = t; j < D_DIM; j += 256) {
        int k = hash_idx[j];
        int pos = atomicAdd(&cnt[k], 1);
        perm16[pos] = (unsigned short)j;    // in-bucket order irrelevant
    }
}

// ---------------------------------------------------------------------------
// Kernel 2: countsketch (unchanged, proven)
// ---------------------------------------------------------------------------
__global__ __launch_bounds__(256) void sketch_gather(
    const float* __restrict__ input,    // [4096][4096]
    const float* __restrict__ weight,   // [4096][4096]
    const float* __restrict__ rand_sgn, // [4096]
    const unsigned int* __restrict__ desc,
    const unsigned short* __restrict__ perm16,
    __hip_bfloat16* __restrict__ sk_in, // [4096][2048]
    __hip_bfloat16* __restrict__ sk_w)  // [4096][2048]
{
    __shared__ __align__(16) float rv0[D_DIM + 8];          // 16.03 KB
    __shared__ __align__(16) float rv1[D_DIM + 8];          // 16.03 KB
    __shared__ __align__(16) unsigned short perm[D_DIM];    // 8 KB
    const int b = blockIdx.x;
    const bool is_w = (b >= NROWS / 2);
    const int pr = is_w ? (b - NROWS / 2) : b;              // row-pair index
    const float* src = (is_w ? weight : input) + (size_t)pr * 2 * D_DIM;
    __hip_bfloat16* dst = (is_w ? sk_w : sk_in) + (size_t)pr * 2 * MB;
    const int t = threadIdx.x;

    const uint4* pg = (const uint4*)perm16;
    ((uint4*)perm)[t]       = pg[t];
    ((uint4*)perm)[t + 256] = pg[t + 256];

    const float4* s4 = (const float4*)src;
    const float4* g4 = (const float4*)rand_sgn;
    #pragma unroll
    for (int i = 0; i < 4; ++i) {
        int q = t + 256 * i;                // float4 granule 0..1023
        float4 g = g4[q];
        float4 x0 = s4[q], x1 = s4[q + 1024];
        float4 y0; y0.x = x0.x*g.x; y0.y = x0.y*g.y; y0.z = x0.z*g.z; y0.w = x0.w*g.w;
        float4 y1; y1.x = x1.x*g.x; y1.y = x1.y*g.y; y1.z = x1.z*g.z; y1.w = x1.w*g.w;
        *(float4*)&rv0[4 * q] = y0;
        *(float4*)&rv1[4 * q] = y1;
    }
    __syncthreads();

    float4 a0[4], a1[4];
    #pragma unroll
    for (int i = 0; i < 4; ++i) {
        int q = t + 256 * i;                // quad of perm slots
        ushort4 pp = *(const ushort4*)&perm[4 * q];
        a0[i].x = rv0[pp.x]; a0[i].y = rv0[pp.y];
        a0[i].z = rv0[pp.z]; a0[i].w = rv0[pp.w];
        a1[i].x = rv1[pp.x]; a1[i].y = rv1[pp.y];
        a1[i].z = rv1[pp.z]; a1[i].w = rv1[pp.w];
    }
    __syncthreads();
    #pragma unroll
    for (int i = 0; i < 4; ++i) {
        int q = t + 256 * i;
        *(float4*)&rv0[4 * q] = a0[i];
        *(float4*)&rv1[4 * q] = a1[i];
    }
    __syncthreads();

    #pragma unroll
    for (int i = 0; i < 8; ++i) {
        int k = t + 256 * i;
        unsigned d = desc[k];
        int st = (int)(d >> 16), c = (int)(d & 0xFFFF);
        float s0 = 0.f, s1 = 0.f;
        #pragma unroll
        for (int j = 0; j < 8; ++j) {
            float v0 = rv0[st + j], v1 = rv1[st + j];
            bool m = (j < c);
            s0 += m ? v0 : 0.f;
            s1 += m ? v1 : 0.f;
        }
        for (int j = 8; j < c; ++j) {
            s0 += rv0[st + j]; s1 += rv1[st + j];
        }
        dst[k]      = __float2bfloat16(s0);
        dst[MB + k] = __float2bfloat16(s1);
    }
}

// ---------------------------------------------------------------------------
// Kernel 3: C = A * B^T + bias. 256x256 tile, BK=64, 8 waves (2Mx4N),
// 8-phase schedule (T3), counted vmcnt(4) (T4), 3-bit row-XOR swizzle (T2,
// 0 conflicts), setprio (T5), XCD rectangle remap (T1, FETCH 77->53MB).
//
// R5 post-mortem: conflicts=0, L2-local, but MfmaUtil pinned at 37% ->
// pipe bubbles are schedule-induced. This round (3 micro-changes, all
// toward the proven m201 shape):
//  (a) MFMA dep spacing: kk OUTERMOST in MFMA_Q -> dependent MFMAs on the
//      same acc are 8 apart (was 1 apart; only 2 waves/SIMD to fill).
//  (b) plain s_barrier (drop sched_barrier(0) pairs; m141: over-pinning
//      defeats compiler scheduling).
//  (c) ONE barrier per phase (post-MFMA only). Safe: every wave's ds_reads
//      are consumed by its own MFMAs (compiler lgkm-waits), so all reads
//      complete before each wave reaches the post-MFMA barrier; stage-DMA
//      for a region still issues only after the barrier following that
//      region's last consumer. VMCNT4 keeps its slot (memory clobber
//      blocks read hoisting above it). R2 rotation audit unchanged.
// ---------------------------------------------------------------------------
#define LDSA(p, h) (lds + (p)*32768 + (h)*16384)
#define LDSB(p, h) (lds + 65536 + (p)*32768 + (h)*16384)
#define SWZ(L) ((L) ^ ((((L) >> 7) & 7) << 4))

#define BAR() __builtin_amdgcn_s_barrier()
#define VMCNT4() asm volatile("s_waitcnt vmcnt(4)" ::: "memory")

// stage A region mh of K-tile kt into buffer p (2 x gld_lds16)
#define STAGE_A(p, mh, kt) do { \
    int L_ = (mh)*8192 + t*16; \
    int P_ = SWZ(L_); \
    const char* s_ = Ab + (size_t)(rowBase + (P_ >> 7)) * 4096 \
                        + (size_t)((((kt) & 31) * 128) + (P_ & 127)); \
    gld_lds16(s_,                       LDSA(p, 0) + L_); \
    gld_lds16(s_ + (size_t)128 * 4096,  LDSA(p, 1) + L_); \
} while (0)

// stage B region nh of K-tile kt into buffer p
#define STAGE_B(p, nh, kt) do { \
    int L_ = (t >> 8) * 8192 + (nh)*4096 + (t & 255) * 16; \
    int P_ = SWZ(L_); \
    const char* s_ = Bb + (size_t)(colBase + (P_ >> 7)) * 4096 \
                        + (size_t)((((kt) & 31) * 128) + (P_ & 127)); \
    gld_lds16(s_,                       LDSB(p, 0) + L_); \
    gld_lds16(s_ + (size_t)128 * 4096,  LDSB(p, 1) + L_); \
} while (0)

// load A fragments for quadrant mh from buffer p (8 x ds_read_b128)
#define LOAD_A(p, mh) do { \
    const char* ba_ = LDSA(p, wm); \
    _Pragma("unroll") \
    for (int i_ = 0; i_ < 4; ++i_) { \
        int r_ = (mh)*64 + i_*16 + mrow; \
        _Pragma("unroll") \
        for (int kk_ = 0; kk_ < 2; ++kk_) { \
            int L_ = r_*128 + kk_*64 + quad*16; \
            af[i_][kk_] = *(const bf16x8*)(ba_ + SWZ(L_)); \
        } \
    } \
} while (0)

// load B fragments for quadrant nh from buffer p into reg set BF
#define LOAD_B(p, nh, BF) do { \
    const char* bb_ = LDSB(p, wn >> 1); \
    _Pragma("unroll") \
    for (int j_ = 0; j_ < 2; ++j_) { \
        int r_ = (wn & 1)*64 + (nh)*32 + j_*16 + mrow; \
        _Pragma("unroll") \
        for (int kk_ = 0; kk_ < 2; ++kk_) { \
            int L_ = r_*128 + kk_*64 + quad*16; \
            BF[j_][kk_] = *(const bf16x8*)(bb_ + SWZ(L_)); \
        } \
    } \
} while (0)

// 16 MFMA: quadrant (mh,nh) x K=64 from reg set BF, setprio-wrapped (T5).
// kk OUTER: dependent-acc MFMAs spaced 8 apart.
#define MFMA_Q(mh, nh, BF) do { \
    __builtin_amdgcn_s_setprio(1); \
    _Pragma("unroll") \
    for (int kk_ = 0; kk_ < 2; ++kk_) \
        _Pragma("unroll") \
        for (int i_ = 0; i_ < 4; ++i_) \
            _Pragma("unroll") \
            for (int j_ = 0; j_ < 2; ++j_) \
                acc[(mh)*4 + i_][(nh)*2 + j_] = \
                    __builtin_amdgcn_mfma_f32_16x16x32_bf16( \
                        af[i_][kk_], BF[j_][kk_], \
                        acc[(mh)*4 + i_][(nh)*2 + j_], 0, 0, 0); \
    __builtin_amdgcn_s_setprio(0); \
} while (0)

__global__ __launch_bounds__(512, 2) void gemm_bt_bias(
    const __hip_bfloat16* __restrict__ A,   // [4096][2048]
    const __hip_bfloat16* __restrict__ B,   // [4096][2048]
    const float* __restrict__ bias,         // [4096]
    float* __restrict__ C)                  // [4096][4096]
{
    __shared__ __align__(16) char lds[131072];   // A: 2x2x16KB | B: 2x2x16KB
    const char* Ab = (const char*)A;
    const char* Bb = (const char*)B;

    const int t = threadIdx.x;
    const int lane = t & 63;
    const int wid  = t >> 6;        // 0..7
    const int wm = wid >> 2;        // 0..1
    const int wn = wid & 3;         // 0..3
    const int quad = lane >> 4;
    const int mrow = lane & 15;

    // XCD rectangle remap (T1): lid%8 = XCD under round-robin dispatch.
    // Each XCD gets an 8(bx) x 4(by) rectangle: L2 K-slice set = 384 KB.
    const int lid  = blockIdx.y * 16 + blockIdx.x;
    const int xcd  = lid & 7;
    const int slot = lid >> 3;                       // 0..31
    const int bx   = (xcd & 1) * 8 + (slot & 7);     // 0..15
    const int by   = (xcd >> 1) * 4 + (slot >> 3);   // 0..15
    const int rowBase = by * 256;
    const int colBase = bx * 256;

    bf16x8 af[4][2];                // A frags, current mh quadrant
    bf16x8 bfr0[2][2];              // B frags, nh=0 (held ph1..ph4)
    bf16x8 bfr1[2][2];              // B frags, nh=1
    floatx4 acc[8][4];
    const floatx4 zero = {0.f, 0.f, 0.f, 0.f};
    #pragma unroll
    for (int i = 0; i < 8; ++i)
        #pragma unroll
        for (int j = 0; j < 4; ++j) acc[i][j] = zero;

    // prologue: kt0 fully (A0,B1,B0,A1 -> buf0), kt1 partially (A0,B1 -> buf1)
    STAGE_A(0, 0, 0); STAGE_B(0, 1, 0); STAGE_B(0, 0, 0); STAGE_A(0, 1, 0);
    STAGE_A(1, 0, 1); STAGE_B(1, 1, 1);
    VMCNT4();          // kt0's 8 loads confirmed; kt1's 4 may fly
    BAR();

    #pragma unroll 1
    for (int it = 0; it < 16; ++it) {
        const int kt = 2 * it;
        // ph1: compute kt.Q(0,0) from buf0; stage kt+1.B0 -> buf1
        LOAD_A(0, 0); LOAD_B(0, 0, bfr0); STAGE_B(1, 0, kt + 1);
        MFMA_Q(0, 0, bfr0); BAR();
        // ph2: Q(0,1); stage kt+1.A1 -> buf1
        LOAD_B(0, 1, bfr1); STAGE_A(1, 1, kt + 1);
        MFMA_Q(0, 1, bfr1); BAR();
        // ph3: Q(1,1), reuse bfr1; stage kt+2.A0 -> buf0 (A0 free after ph2)
        LOAD_A(0, 1); STAGE_A(0, 0, kt + 2);
        MFMA_Q(1, 1, bfr1); BAR();
        // ph4: Q(1,0), reuse bfr0 (no LDS reads); stage kt+2.B1 -> buf0
        STAGE_B(0, 1, kt + 2);
        MFMA_Q(1, 0, bfr0); VMCNT4(); BAR();
        // ph5: compute kt+1.Q(0,0) from buf1; stage kt+2.B0 -> buf0
        LOAD_A(1, 0); LOAD_B(1, 0, bfr0); STAGE_B(0, 0, kt + 2);
        MFMA_Q(0, 0, bfr0); BAR();
        // ph6: Q(0,1); stage kt+2.A1 -> buf0
        LOAD_B(1, 1, bfr1); STAGE_A(0, 1, kt + 2);
        MFMA_Q(0, 1, bfr1); BAR();
        // ph7: Q(1,1), reuse bfr1; stage kt+3.A0 -> buf1 (A0 free after ph6)
        LOAD_A(1, 1); STAGE_A(1, 0, kt + 3);
        MFMA_Q(1, 1, bfr1); BAR();
        // ph8: Q(1,0), reuse bfr0 (no LDS reads); stage kt+3.B1 -> buf1
        STAGE_B(1, 1, kt + 3);
        MFMA_Q(1, 0, bfr0); VMCNT4(); BAR();
    }

    // epilogue: C/D layout col=lane&15, row=quad*4+reg  [m89/m91]
    float bj[4];
    #pragma unroll
    for (int j = 0; j < 4; ++j)
        bj[j] = bias[colBase + wn * 64 + j * 16 + mrow];
    #pragma unroll
    for (int i = 0; i < 8; ++i) {
        int m0 = rowBase + wm * 128 + i * 16 + quad * 4;
        #pragma unroll
        for (int j = 0; j < 4; ++j) {
            int n = colBase + wn * 64 + j * 16 + mrow;
            #pragma unroll
            for (int p = 0; p < 4; ++p)
                C[(size_t)(m0 + p) * NROWS + n] = acc[i][j][p] + bj[j];
        }
    }
}

// ---------------------------------------------------------------------------
extern "C" void kernel_launch(void* const* d_in, const int* in_sizes, int n_in,
                              void* d_out, int out_size, void* d_ws, size_t ws_size,
                              hipStream_t stream) {
    const float* input  = (const float*)d_in[0];
    const float* weight = (const float*)d_in[1];
    const float* bias   = (const float*)d_in[2];
    const int*   hidx   = (const int*)d_in[3];
    const float* sgn    = (const float*)d_in[4];
    float* out = (float*)d_out;

    // workspace: sk_in 16MB | sk_w 16MB | desc 8KB | perm16 8KB
    char* ws = (char*)d_ws;
    __hip_bfloat16* sk_in = (__hip_bfloat16*)ws;
    __hip_bfloat16* sk_w  = (__hip_bfloat16*)(ws + (size_t)16 * 1024 * 1024);
    unsigned int*   desc  = (unsigned int*)(ws + (size_t)32 * 1024 * 1024);
    unsigned short* perm16 = (unsigned short*)(ws + (size_t)32 * 1024 * 1024 + 8192);

    build_csr<<<1, 256, 0, stream>>>(hidx, desc, perm16);
    sketch_gather<<<NROWS, 256, 0, stream>>>(input, weight, sgn, desc, perm16,
                                             sk_in, sk_w);
    gemm_bt_bias<<<dim3(16, 16), 512, 0, stream>>>(sk_in, sk_w, bias, out);
}